// Round 7
// baseline (28.708 us; speedup 1.0000x reference)
//
#include <hip/hip_runtime.h>
#include <math.h>

// FRN projection head, MI355X — single fused kernel, R7: smaller grid.
// Math: hat = (StS+lam I)^-1 StS = I - lam*Minv ; B = rho*hat - I (symmetric)
//       G = B^2 ; neg_l2[img,n] = -(1/100) <G_n, C_img>,  C_img = A A^T (Gram)
// Minv via Gershgorin-bounded Chebyshev-1 init + 2 Newton-Schulz iterations.
// R7 layout (grid 92 x 256, 64KB LDS -> 2 blk/CU -> 512 slots >= 92: safe):
//  - b 0..29 : support-Gram partials (5 imgs, 4-wave k-split)  [R5 verbatim]
//  - b 30..34: DEDICATED per-class solve (poll 6 gflags, NS)   [R5 verbatim]
//  - b 35..91: query, 8 imgs/block (2 per wave, grams overlap solve)
//  - b 35    : gathers 57 per-block loss partials (fixed order)
// Sync: R5's relaxed-poll + single acquire fence; release fence + flag store.
// Rationale: dispatch ramp scales with grid size and the tail block's flag is
// on the critical path; 305-blk variants (R4/R6) regressed, so shrink to 92.

typedef __attribute__((ext_vector_type(8))) short short8;   // 8 x bf16 bits
typedef __attribute__((ext_vector_type(4))) short short4v;  // 4 x bf16 bits
typedef __attribute__((ext_vector_type(4))) float f32x4;

#define NSUP 150
#define NQ 450
#define PIX 100
#define IMG_STRIDE 6400   // 64*100 floats per image
#define MAGIC 0x5F3D2B1Cu

static __device__ __forceinline__ short bf16r(float x) {   // f32 -> bf16 (RNE)
  unsigned u = __builtin_bit_cast(unsigned, x);
  u += 0x7FFFu + ((u >> 16) & 1u);
  return (short)(u >> 16);
}
static __device__ __forceinline__ float b2f(short v) {
  return __builtin_bit_cast(float, ((unsigned)(unsigned short)v) << 16);
}
// producer: one agent release fence (writeback), then relaxed flag store.
static __device__ __forceinline__ void st_flag(unsigned* p, unsigned v) {
  __builtin_amdgcn_fence(__ATOMIC_RELEASE, "agent");
  __hip_atomic_store(p, v, __ATOMIC_RELAXED, __HIP_MEMORY_SCOPE_AGENT);
}
// consumer poll: relaxed (no per-poll invalidate); caller fences ACQUIRE after.
static __device__ __forceinline__ void spin_rlx(unsigned* p) {
  int guard = 1 << 22;
  while (__hip_atomic_load(p, __ATOMIC_RELAXED, __HIP_MEMORY_SCOPE_AGENT) != MAGIC
         && --guard) __builtin_amdgcn_s_sleep(2);
}

// Accumulate acc += A*A^T for one image (A = 64x100 f32, k padded to 128).
// C/D layout: row = R*16 + (lane>>4)*4 + q, col = C*16 + (lane&15).
static __device__ __forceinline__ void gram_accum(const float* __restrict__ f,
                                                  f32x4 acc[4][4], int r, int g) {
  #pragma unroll
  for (int ks = 0; ks < 4; ++ks) {
    short8 frag[4];
    const int kb = ks * 32 + g * 8;
    #pragma unroll
    for (int R = 0; R < 4; ++R) {
      short8 q;
      const float* p = f + (R * 16 + r) * PIX + kb;
      if (ks < 3) {
        float4 lo = *(const float4*)p;
        float4 hi = *(const float4*)(p + 4);
        q[0] = bf16r(lo.x); q[1] = bf16r(lo.y); q[2] = bf16r(lo.z); q[3] = bf16r(lo.w);
        q[4] = bf16r(hi.x); q[5] = bf16r(hi.y); q[6] = bf16r(hi.z); q[7] = bf16r(hi.w);
      } else if (g == 0) {                 // k = 96..99 valid, rest zero-pad
        float4 lo = *(const float4*)p;
        q[0] = bf16r(lo.x); q[1] = bf16r(lo.y); q[2] = bf16r(lo.z); q[3] = bf16r(lo.w);
        q[4] = 0; q[5] = 0; q[6] = 0; q[7] = 0;
      } else {
        #pragma unroll
        for (int j = 0; j < 8; ++j) q[j] = 0;
      }
      frag[R] = q;
    }
    #pragma unroll
    for (int R = 0; R < 4; ++R)
      #pragma unroll
      for (int C = 0; C < 4; ++C)
        acc[R][C] = __builtin_amdgcn_mfma_f32_16x16x32_bf16(frag[R], frag[C],
                                                            acc[R][C], 0, 0, 0);
  }
}

// Quadrant (wr,wc) of D = A*B for 64x64 bf16 LDS matrices (stride 72).
// B must be SYMMETRIC (B-fragment gathered as rows of B).
static __device__ __forceinline__ void mm64q(const short* A, const short* B,
                                             f32x4 t[2][2], int r, int g,
                                             int wr, int wc) {
  #pragma unroll
  for (int ks = 0; ks < 2; ++ks) {
    short8 af[2], bfr[2];
    #pragma unroll
    for (int i = 0; i < 2; ++i) {
      af[i]  = *(const short8*)(A + (wr * 32 + i * 16 + r) * 72 + ks * 32 + g * 8);
      bfr[i] = *(const short8*)(B + (wc * 32 + i * 16 + r) * 72 + ks * 32 + g * 8);
    }
    #pragma unroll
    for (int i = 0; i < 2; ++i)
      #pragma unroll
      for (int j = 0; j < 2; ++j)
        t[i][j] = __builtin_amdgcn_mfma_f32_16x16x32_bf16(af[i], bfr[j],
                                                          t[i][j], 0, 0, 0);
  }
}

// partial <Gneg_n, C> dot (this wave's fragment share) + wave reduce.
static __device__ __forceinline__ void dot5(const f32x4 acc[4][4],
                                            const unsigned short* Gs,
                                            int r, int g, float nl[5]) {
  #pragma unroll
  for (int nn = 0; nn < 5; ++nn) nl[nn] = 0.f;
  #pragma unroll
  for (int R = 0; R < 4; ++R)
    #pragma unroll
    for (int C = 0; C < 4; ++C)
      #pragma unroll
      for (int q = 0; q < 4; ++q) {
        const int row = R * 16 + g * 4 + q, col = C * 16 + r;
        const float cv = acc[R][C][q] * (1.f / 64.f);
        const int idx = row * 68 + col;
        #pragma unroll
        for (int nn = 0; nn < 5; ++nn)
          nl[nn] += b2f((short)Gs[nn * 4352 + idx]) * cv;
      }
  #pragma unroll
  for (int nn = 0; nn < 5; ++nn)
    for (int off = 32; off; off >>= 1) nl[nn] += __shfl_down(nl[nn], off);
}

#define ZERO_ACC4(t)                                  \
  _Pragma("unroll") for (int R = 0; R < 4; ++R)       \
  _Pragma("unroll") for (int C = 0; C < 4; ++C)       \
  _Pragma("unroll") for (int q = 0; q < 4; ++q) t[R][C][q] = 0.f;

#define ZERO_ACC2(t)                                  \
  _Pragma("unroll") for (int R = 0; R < 2; ++R)       \
  _Pragma("unroll") for (int C = 0; C < 2; ++C)       \
  _Pragma("unroll") for (int q = 0; q < 4; ++q) t[R][C][q] = 0.f;

__global__ __launch_bounds__(256) void k_fused(
    const float* __restrict__ feat, const int* __restrict__ label,
    const float* __restrict__ scale, const float* __restrict__ rvec,
    float* __restrict__ out,
    float* __restrict__ partial,            // 30*4096 f32
    unsigned short* __restrict__ Gneg,      // 5*4096 bf16 (-B^2/100)
    float* __restrict__ blockloss,          // 57 f32
    unsigned* __restrict__ gflag,           // 30
    unsigned* __restrict__ sflag,           // 5
    unsigned* __restrict__ lflag) {         // 57
  __shared__ __align__(16) char smem[65536];
  const int b = blockIdx.x, tid = threadIdx.x;
  const int wave = tid >> 6, lane = tid & 63;
  const int r = lane & 15, g = lane >> 4;

  if (b < 30) {
    // ================= support-Gram partial (class b/6, group b%6) ==========
    float (*gbuf)[4096] = (float (*)[4096])smem;
    const int cls = b / 6, jb = b % 6;
    const int ks = wave, kb = ks * 32 + g * 8;
    f32x4 acc[4][4];
    ZERO_ACC4(acc)
    for (int im = 0; im < 5; ++im) {
      const float* f = feat + (size_t)(cls * 30 + jb * 5 + im) * IMG_STRIDE;
      short8 frag[4];
      #pragma unroll
      for (int R = 0; R < 4; ++R) {
        short8 q;
        const float* p = f + (R * 16 + r) * PIX + kb;
        if (ks < 3) {
          float4 lo = *(const float4*)p;
          float4 hi = *(const float4*)(p + 4);
          q[0] = bf16r(lo.x); q[1] = bf16r(lo.y); q[2] = bf16r(lo.z); q[3] = bf16r(lo.w);
          q[4] = bf16r(hi.x); q[5] = bf16r(hi.y); q[6] = bf16r(hi.z); q[7] = bf16r(hi.w);
        } else if (g == 0) {
          float4 lo = *(const float4*)p;
          q[0] = bf16r(lo.x); q[1] = bf16r(lo.y); q[2] = bf16r(lo.z); q[3] = bf16r(lo.w);
          q[4] = 0; q[5] = 0; q[6] = 0; q[7] = 0;
        } else {
          #pragma unroll
          for (int j = 0; j < 8; ++j) q[j] = 0;
        }
        frag[R] = q;
      }
      #pragma unroll
      for (int R = 0; R < 4; ++R)
        #pragma unroll
        for (int C = 0; C < 4; ++C)
          acc[R][C] = __builtin_amdgcn_mfma_f32_16x16x32_bf16(frag[R], frag[C],
                                                              acc[R][C], 0, 0, 0);
    }
    #pragma unroll
    for (int R = 0; R < 4; ++R)
      #pragma unroll
      for (int C = 0; C < 4; ++C)
        #pragma unroll
        for (int q = 0; q < 4; ++q) {
          const int row = R * 16 + g * 4 + q, col = C * 16 + r;
          gbuf[wave][row * 64 + col] = acc[R][C][q];
        }
    __syncthreads();
    float* outp = partial + (size_t)b * 4096;
    for (int c = tid; c < 1024; c += 256) {
      f32x4 s0 = *(const f32x4*)&gbuf[0][4 * c];
      f32x4 s1 = *(const f32x4*)&gbuf[1][4 * c];
      f32x4 s2 = *(const f32x4*)&gbuf[2][4 * c];
      f32x4 s3 = *(const f32x4*)&gbuf[3][4 * c];
      f32x4 s = s0 + s1 + s2 + s3;
      *(float4*)(outp + 4 * c) = *(float4*)&s;
    }
    __syncthreads();
    if (tid == 0) st_flag(&gflag[b], MAGIC);
    return;
  }

  if (b < 35) {
    // ================ per-class solve (class n = b-30, dedicated) ===========
    float* Ms   = (float*)(smem);            // 64*65 f32
    short* Mb   = (short*)(smem + 16640);    // 64*72 bf16
    short* Tb   = (short*)(smem + 25856);
    short* Xa   = (short*)(smem + 35072);
    short* Xc   = (short*)(smem + 44288);
    float* radp = (float*)(smem + 53504);    // [4][64]
    float* scal = (float*)(smem + 54528);    // sS, sTheta

    const int n = b - 30;
    const int wr = wave >> 1, wc = wave & 1;
    const float lam = 46.875f * expf(rvec[0]);   // reg = 3000/64
    const float rho = expf(rvec[1]);

    if (tid < 6) spin_rlx(&gflag[6 * n + tid]);
    __syncthreads();
    __builtin_amdgcn_fence(__ATOMIC_ACQUIRE, "agent");   // one inv per wave

    {  // M = (1/64) * sum of 6 partials (+ lam on diag)
      const float* base = partial + (size_t)n * 6 * 4096;
      for (int c = tid; c < 1024; c += 256) {
        float4 s = {0.f, 0.f, 0.f, 0.f};
        #pragma unroll
        for (int p = 0; p < 6; ++p) {
          float4 v = *(const float4*)(base + p * 4096 + 4 * c);
          s.x += v.x; s.y += v.y; s.z += v.z; s.w += v.w;
        }
        const int e = 4 * c, row = e >> 6, col = e & 63;
        Ms[row * 65 + col + 0] = s.x * (1.f / 64.f);
        Ms[row * 65 + col + 1] = s.y * (1.f / 64.f);
        Ms[row * 65 + col + 2] = s.z * (1.f / 64.f);
        Ms[row * 65 + col + 3] = s.w * (1.f / 64.f);
      }
    }
    __syncthreads();
    if (tid < 64) Ms[tid * 65 + tid] += lam;
    __syncthreads();

    {  // Gershgorin (4 threads/row) -> Chebyshev-1 init params
      const int row = tid & 63, part = tid >> 6;
      float s = 0.f;
      #pragma unroll
      for (int k = 0; k < 16; ++k) s += fabsf(Ms[row * 65 + part * 16 + k]);
      radp[part * 64 + row] = s;
    }
    __syncthreads();
    if (tid < 64) {
      const float diag = Ms[tid * 65 + tid];
      const float rad = radp[tid] + radp[64 + tid] + radp[128 + tid] +
                        radp[192 + tid] - fabsf(diag);
      float lo = diag - rad, hi = diag + rad;
      for (int off = 32; off; off >>= 1) {
        lo = fminf(lo, __shfl_down(lo, off));
        hi = fmaxf(hi, __shfl_down(hi, off));
      }
      if (tid == 0) {
        const float a = fmaxf(lo, lam);   // spectrum >= lam (StS is PSD)
        const float bb = hi;
        const float s = a + bb, d = bb - a;
        scal[0] = s;
        scal[1] = 8.f / (2.f * s * s - d * d);   // X0 = theta*(s*I - M)
      }
    }
    __syncthreads();
    const float s0 = scal[0], theta = scal[1];

    for (int e = tid; e < 4096; e += 256) {      // Mb, X0
      const int i = e >> 6, j = e & 63;
      const float m = Ms[i * 65 + j];
      Mb[i * 72 + j] = bf16r(m);
      Xa[i * 72 + j] = bf16r(theta * (((i == j) ? s0 : 0.f) - m));
    }
    __syncthreads();

    short* x = Xa;                               // 2 Newton-Schulz iterations
    short* xn = Xc;
    for (int it = 0; it < 2; ++it) {
      {
        f32x4 t[2][2];
        ZERO_ACC2(t)
        mm64q(x, Mb, t, r, g, wr, wc);           // T = X*M (M symmetric)
        #pragma unroll
        for (int i = 0; i < 2; ++i)
          #pragma unroll
          for (int j = 0; j < 2; ++j)
            #pragma unroll
            for (int q = 0; q < 4; ++q) {
              const int row = wr * 32 + i * 16 + g * 4 + q;
              const int col = wc * 32 + j * 16 + r;
              Tb[row * 72 + col] = bf16r(t[i][j][q]);
            }
      }
      __syncthreads();
      {
        f32x4 t[2][2];
        ZERO_ACC2(t)
        mm64q(Tb, x, t, r, g, wr, wc);           // T*X (X ~symmetric)
        #pragma unroll
        for (int i = 0; i < 2; ++i)
          #pragma unroll
          for (int j = 0; j < 2; ++j)
            #pragma unroll
            for (int q = 0; q < 4; ++q) {
              const int row = wr * 32 + i * 16 + g * 4 + q;
              const int col = wc * 32 + j * 16 + r;
              const int idx = row * 72 + col;
              xn[idx] = bf16r(2.f * b2f(x[idx]) - t[i][j][q]);
            }
      }
      __syncthreads();
      short* tmp = x; x = xn; xn = tmp;
    }

    for (int e = tid; e < 4096; e += 256) {      // B = (rho-1)I - rho*lam*X
      const int i = e >> 6, j = e & 63;
      const float xv = b2f(x[i * 72 + j]);
      Tb[i * 72 + j] = bf16r(((i == j) ? (rho - 1.f) : 0.f) - rho * lam * xv);
    }
    __syncthreads();

    {  // G = B*B ; store bf16(-G/100)
      f32x4 t[2][2];
      ZERO_ACC2(t)
      mm64q(Tb, Tb, t, r, g, wr, wc);
      #pragma unroll
      for (int i = 0; i < 2; ++i)
        #pragma unroll
        for (int j = 0; j < 2; ++j)
          #pragma unroll
          for (int q = 0; q < 4; ++q) {
            const int row = wr * 32 + i * 16 + g * 4 + q;
            const int col = wc * 32 + j * 16 + r;
            Gneg[n * 4096 + row * 64 + col] =
                (unsigned short)bf16r(t[i][j][q] * (-0.01f));
          }
    }
    __syncthreads();
    if (tid == 0) st_flag(&sflag[n], MAGIC);
    return;
  }

  // ========== query: 8 imgs/block; wave w -> imgs base+w, base+4+w ==========
  const int qb = b - 35;                   // 0..56
  const int base = qb * 8;
  const int imgA = base + wave, imgB = base + 4 + wave;
  const bool okA = imgA < NQ, okB = imgB < NQ;
  f32x4 accA[4][4], accB[4][4];
  ZERO_ACC4(accA)
  ZERO_ACC4(accB)
  if (okA)                                 // overlaps the solve
    gram_accum(feat + (size_t)(NSUP + imgA) * IMG_STRIDE, accA, r, g);
  if (okB)
    gram_accum(feat + (size_t)(NSUP + imgB) * IMG_STRIDE, accB, r, g);

  if (tid < 5) spin_rlx(&sflag[tid]);
  __syncthreads();
  __builtin_amdgcn_fence(__ATOMIC_ACQUIRE, "agent");   // one inv per wave

  // stage G (bf16) into LDS, row stride 68 (bank-spread, 8B aligned writes)
  unsigned short* Gs = (unsigned short*)smem;   // 5*64*68 ushorts = 43520 B
  for (int e = tid; e < 5120; e += 256) {
    const int e4 = e * 4;
    const int nn = e4 >> 12, rem = e4 & 4095, row = rem >> 6, col = rem & 63;
    *(short4v*)&Gs[nn * 4352 + row * 68 + col] = *(const short4v*)&Gneg[e4];
  }
  __syncthreads();

  float* wl = (float*)(smem + 43584);      // [8] per-image losses
  const float sc = scale[0];
  for (int h = 0; h < 2; ++h) {
    const bool ok = h ? okB : okA;
    const int img = h ? imgB : imgA;
    if (ok) {
      float nl[5];
      dot5(h ? accB : accA, Gs, r, g, nl);
      if (lane == 0) {
        float mx = nl[0];
        #pragma unroll
        for (int nn = 1; nn < 5; ++nn) mx = fmaxf(mx, nl[nn]);
        float ex[5], se = 0.f;
        #pragma unroll
        for (int nn = 0; nn < 5; ++nn) { ex[nn] = expf(nl[nn] - mx); se += ex[nn]; }
        const float inv = 1.f / se;
        #pragma unroll
        for (int nn = 0; nn < 5; ++nn) out[img * 5 + nn] = ex[nn] * inv;

        float mx2 = nl[0] * sc;
        #pragma unroll
        for (int nn = 1; nn < 5; ++nn) mx2 = fmaxf(mx2, nl[nn] * sc);
        float se2 = 0.f;
        #pragma unroll
        for (int nn = 0; nn < 5; ++nn) se2 += expf(nl[nn] * sc - mx2);
        wl[wave * 2 + h] = mx2 + logf(se2) - nl[label[img]] * sc;
      }
    } else if (lane == 0) {
      wl[wave * 2 + h] = 0.f;
    }
  }
  __syncthreads();
  if (tid == 0) {
    float s = 0.f;
    #pragma unroll
    for (int i = 0; i < 8; ++i) s += wl[i];
    blockloss[qb] = s;
    st_flag(&lflag[qb], MAGIC);
  }

  if (qb == 0 && wave == 0) {              // final loss gather (block 35)
    for (int i = lane; i < 57; i += 64) spin_rlx(&lflag[i]);
    __builtin_amdgcn_fence(__ATOMIC_ACQUIRE, "agent");
    float s = 0.f;
    for (int i = lane; i < 57; i += 64) s += blockloss[i];
    for (int off = 32; off; off >>= 1) s += __shfl_down(s, off);
    if (lane == 0) out[2250] = s / 450.f;
  }
}

extern "C" void kernel_launch(void* const* d_in, const int* in_sizes, int n_in,
                              void* d_out, int out_size, void* d_ws, size_t ws_size,
                              hipStream_t stream) {
  const float* feat  = (const float*)d_in[0];
  const int*   label = (const int*)d_in[1];
  const float* scale = (const float*)d_in[2];
  const float* rvec  = (const float*)d_in[3];
  float* out = (float*)d_out;

  char* ws = (char*)d_ws;
  float*          partial   = (float*)ws;                  //      0 .. 491520
  unsigned short* Gneg      = (unsigned short*)(ws + 491520);   // 40960 B
  float*          blockloss = (float*)(ws + 532480);       //   228 B
  unsigned*       flags     = (unsigned*)(ws + 532992);
  unsigned* gflag = flags;         // 30
  unsigned* sflag = flags + 32;    // 5
  unsigned* lflag = flags + 64;    // 57

  k_fused<<<dim3(92), dim3(256), 0, stream>>>(feat, label, scale, rvec, out,
                                              partial, Gneg, blockloss,
                                              gflag, sflag, lflag);
}

// Round 8
// 24.444 us; speedup vs baseline: 1.1744x; 1.1744x over previous
//
#include <hip/hip_runtime.h>
#include <math.h>

// FRN projection head, MI355X — single fused kernel, R8 = R5 + phase fusion.
// Math: hat = (StS+lam I)^-1 StS = I - lam*Minv ; B = rho*hat - I (symmetric)
//       G = B^2 ; neg_l2[img,n] = -(1/100) <G_n, C_img>,  C_img = A A^T (Gram)
// Minv via Gershgorin-bounded Chebyshev-1 init + 2 Newton-Schulz iterations.
// R8 changes vs R5 (best, 24.4us):
//  - solve: lam+Mb fused into sum phase; B fused into NS-2 output (11->9 phases)
//  - sum phase and support im-loop unrolled (more loads in flight)
//  - query: G staged at stride 80 (bank-conflict-free dot); sc/label pre-loaded
// Topology unchanged: 143 blocks x 256, 64KB LDS, 2 blk/CU, all co-resident.
//  - blocks 0..29 : support-Gram partials (5 imgs, 4-wave k-split) -> gflag
//  - blocks 0..4  : + per-class solve (quadrant NS on 4 waves) -> G bf16, sflag
//  - blocks 30..142: query Grams in regs (overlap solve), wait, dot, softmax
//  - block 30     : gathers 113 per-block loss partials (fixed order)

typedef __attribute__((ext_vector_type(8))) short short8;   // 8 x bf16 bits
typedef __attribute__((ext_vector_type(4))) short short4v;  // 4 x bf16 bits
typedef __attribute__((ext_vector_type(4))) float f32x4;

#define NSUP 150
#define NQ 450
#define PIX 100
#define IMG_STRIDE 6400   // 64*100 floats per image
#define MAGIC 0x5F3D2B1Cu

static __device__ __forceinline__ short bf16r(float x) {   // f32 -> bf16 (RNE)
  unsigned u = __builtin_bit_cast(unsigned, x);
  u += 0x7FFFu + ((u >> 16) & 1u);
  return (short)(u >> 16);
}
static __device__ __forceinline__ float b2f(short v) {
  return __builtin_bit_cast(float, ((unsigned)(unsigned short)v) << 16);
}
// producer: one agent release fence (writeback), then relaxed flag store.
static __device__ __forceinline__ void st_flag(unsigned* p, unsigned v) {
  __builtin_amdgcn_fence(__ATOMIC_RELEASE, "agent");
  __hip_atomic_store(p, v, __ATOMIC_RELAXED, __HIP_MEMORY_SCOPE_AGENT);
}
// consumer poll: relaxed (no per-poll invalidate); caller fences ACQUIRE after.
static __device__ __forceinline__ void spin_rlx(unsigned* p) {
  int guard = 1 << 22;
  while (__hip_atomic_load(p, __ATOMIC_RELAXED, __HIP_MEMORY_SCOPE_AGENT) != MAGIC
         && --guard) __builtin_amdgcn_s_sleep(2);
}

// Accumulate acc += A*A^T for one image (A = 64x100 f32, k padded to 128).
// C/D layout: row = R*16 + (lane>>4)*4 + q, col = C*16 + (lane&15).
static __device__ __forceinline__ void gram_accum(const float* __restrict__ f,
                                                  f32x4 acc[4][4], int r, int g) {
  #pragma unroll
  for (int ks = 0; ks < 4; ++ks) {
    short8 frag[4];
    const int kb = ks * 32 + g * 8;
    #pragma unroll
    for (int R = 0; R < 4; ++R) {
      short8 q;
      const float* p = f + (R * 16 + r) * PIX + kb;
      if (ks < 3) {
        float4 lo = *(const float4*)p;
        float4 hi = *(const float4*)(p + 4);
        q[0] = bf16r(lo.x); q[1] = bf16r(lo.y); q[2] = bf16r(lo.z); q[3] = bf16r(lo.w);
        q[4] = bf16r(hi.x); q[5] = bf16r(hi.y); q[6] = bf16r(hi.z); q[7] = bf16r(hi.w);
      } else if (g == 0) {                 // k = 96..99 valid, rest zero-pad
        float4 lo = *(const float4*)p;
        q[0] = bf16r(lo.x); q[1] = bf16r(lo.y); q[2] = bf16r(lo.z); q[3] = bf16r(lo.w);
        q[4] = 0; q[5] = 0; q[6] = 0; q[7] = 0;
      } else {
        #pragma unroll
        for (int j = 0; j < 8; ++j) q[j] = 0;
      }
      frag[R] = q;
    }
    #pragma unroll
    for (int R = 0; R < 4; ++R)
      #pragma unroll
      for (int C = 0; C < 4; ++C)
        acc[R][C] = __builtin_amdgcn_mfma_f32_16x16x32_bf16(frag[R], frag[C],
                                                            acc[R][C], 0, 0, 0);
  }
}

// Quadrant (wr,wc) of D = A*B for 64x64 bf16 LDS matrices (stride 72).
// B must be SYMMETRIC (B-fragment gathered as rows of B).
static __device__ __forceinline__ void mm64q(const short* A, const short* B,
                                             f32x4 t[2][2], int r, int g,
                                             int wr, int wc) {
  #pragma unroll
  for (int ks = 0; ks < 2; ++ks) {
    short8 af[2], bfr[2];
    #pragma unroll
    for (int i = 0; i < 2; ++i) {
      af[i]  = *(const short8*)(A + (wr * 32 + i * 16 + r) * 72 + ks * 32 + g * 8);
      bfr[i] = *(const short8*)(B + (wc * 32 + i * 16 + r) * 72 + ks * 32 + g * 8);
    }
    #pragma unroll
    for (int i = 0; i < 2; ++i)
      #pragma unroll
      for (int j = 0; j < 2; ++j)
        t[i][j] = __builtin_amdgcn_mfma_f32_16x16x32_bf16(af[i], bfr[j],
                                                          t[i][j], 0, 0, 0);
  }
}

#define ZERO_ACC4(t)                                  \
  _Pragma("unroll") for (int R = 0; R < 4; ++R)       \
  _Pragma("unroll") for (int C = 0; C < 4; ++C)       \
  _Pragma("unroll") for (int q = 0; q < 4; ++q) t[R][C][q] = 0.f;

#define ZERO_ACC2(t)                                  \
  _Pragma("unroll") for (int R = 0; R < 2; ++R)       \
  _Pragma("unroll") for (int C = 0; C < 2; ++C)       \
  _Pragma("unroll") for (int q = 0; q < 4; ++q) t[R][C][q] = 0.f;

__global__ __launch_bounds__(256) void k_fused(
    const float* __restrict__ feat, const int* __restrict__ label,
    const float* __restrict__ scale, const float* __restrict__ rvec,
    float* __restrict__ out,
    float* __restrict__ partial,            // 30*4096 f32
    unsigned short* __restrict__ Gneg,      // 5*4096 bf16 (-B^2/100)
    float* __restrict__ blockloss,          // 113 f32
    unsigned* __restrict__ gflag,           // 30
    unsigned* __restrict__ sflag,           // 5
    unsigned* __restrict__ lflag) {         // 113
  __shared__ __align__(16) char smem[65536];
  const int b = blockIdx.x, tid = threadIdx.x;
  const int wave = tid >> 6, lane = tid & 63;
  const int r = lane & 15, g = lane >> 4;

  if (b < 30) {
    // ================= support-Gram partial (class b/6, group b%6) ==========
    float (*gbuf)[4096] = (float (*)[4096])smem;
    const int cls = b / 6, jb = b % 6;
    const int ks = wave, kb = ks * 32 + g * 8;
    f32x4 acc[4][4];
    ZERO_ACC4(acc)
    #pragma unroll
    for (int im = 0; im < 5; ++im) {
      const float* f = feat + (size_t)(cls * 30 + jb * 5 + im) * IMG_STRIDE;
      short8 frag[4];
      #pragma unroll
      for (int R = 0; R < 4; ++R) {
        short8 q;
        const float* p = f + (R * 16 + r) * PIX + kb;
        if (ks < 3) {
          float4 lo = *(const float4*)p;
          float4 hi = *(const float4*)(p + 4);
          q[0] = bf16r(lo.x); q[1] = bf16r(lo.y); q[2] = bf16r(lo.z); q[3] = bf16r(lo.w);
          q[4] = bf16r(hi.x); q[5] = bf16r(hi.y); q[6] = bf16r(hi.z); q[7] = bf16r(hi.w);
        } else if (g == 0) {
          float4 lo = *(const float4*)p;
          q[0] = bf16r(lo.x); q[1] = bf16r(lo.y); q[2] = bf16r(lo.z); q[3] = bf16r(lo.w);
          q[4] = 0; q[5] = 0; q[6] = 0; q[7] = 0;
        } else {
          #pragma unroll
          for (int j = 0; j < 8; ++j) q[j] = 0;
        }
        frag[R] = q;
      }
      #pragma unroll
      for (int R = 0; R < 4; ++R)
        #pragma unroll
        for (int C = 0; C < 4; ++C)
          acc[R][C] = __builtin_amdgcn_mfma_f32_16x16x32_bf16(frag[R], frag[C],
                                                              acc[R][C], 0, 0, 0);
    }
    #pragma unroll
    for (int R = 0; R < 4; ++R)
      #pragma unroll
      for (int C = 0; C < 4; ++C)
        #pragma unroll
        for (int q = 0; q < 4; ++q) {
          const int row = R * 16 + g * 4 + q, col = C * 16 + r;
          gbuf[wave][row * 64 + col] = acc[R][C][q];
        }
    __syncthreads();
    float* outp = partial + (size_t)b * 4096;
    for (int c = tid; c < 1024; c += 256) {
      f32x4 s0 = *(const f32x4*)&gbuf[0][4 * c];
      f32x4 s1 = *(const f32x4*)&gbuf[1][4 * c];
      f32x4 s2 = *(const f32x4*)&gbuf[2][4 * c];
      f32x4 s3 = *(const f32x4*)&gbuf[3][4 * c];
      f32x4 s = s0 + s1 + s2 + s3;
      *(float4*)(outp + 4 * c) = *(float4*)&s;
    }
    __syncthreads();                         // gbuf dead; smem reused below
    if (tid == 0) st_flag(&gflag[b], MAGIC);
    if (b >= 5) return;

    // ======================= per-class solve (class n = b) ==================
    float* Ms   = (float*)(smem);            // 64*65 f32
    short* Mb   = (short*)(smem + 16640);    // 64*72 bf16
    short* Tb   = (short*)(smem + 25856);
    short* Xa   = (short*)(smem + 35072);
    short* Xc   = (short*)(smem + 44288);
    float* radp = (float*)(smem + 53504);    // [4][64]
    float* scal = (float*)(smem + 54528);    // sS, sTheta

    const int n = b;
    const int wr = wave >> 1, wc = wave & 1;
    const float lam = 46.875f * expf(rvec[0]);   // reg = 3000/64
    const float rho = expf(rvec[1]);

    if (tid < 6) spin_rlx(&gflag[6 * n + tid]);
    __syncthreads();
    __builtin_amdgcn_fence(__ATOMIC_ACQUIRE, "agent");   // one inv per wave

    {  // M = (1/64)*sum of 6 partials, + lam on diag, + bf16 Mb — one pass
      const float* base = partial + (size_t)n * 6 * 4096;
      #pragma unroll
      for (int c0 = 0; c0 < 4; ++c0) {
        const int c = tid + c0 * 256;
        float4 s = {0.f, 0.f, 0.f, 0.f};
        #pragma unroll
        for (int p = 0; p < 6; ++p) {
          float4 v = *(const float4*)(base + p * 4096 + 4 * c);
          s.x += v.x; s.y += v.y; s.z += v.z; s.w += v.w;
        }
        const int e = 4 * c, row = e >> 6, col = e & 63;
        const float m0 = s.x * (1.f / 64.f) + ((row == col    ) ? lam : 0.f);
        const float m1 = s.y * (1.f / 64.f) + ((row == col + 1) ? lam : 0.f);
        const float m2 = s.z * (1.f / 64.f) + ((row == col + 2) ? lam : 0.f);
        const float m3 = s.w * (1.f / 64.f) + ((row == col + 3) ? lam : 0.f);
        Ms[row * 65 + col + 0] = m0;
        Ms[row * 65 + col + 1] = m1;
        Ms[row * 65 + col + 2] = m2;
        Ms[row * 65 + col + 3] = m3;
        Mb[row * 72 + col + 0] = bf16r(m0);
        Mb[row * 72 + col + 1] = bf16r(m1);
        Mb[row * 72 + col + 2] = bf16r(m2);
        Mb[row * 72 + col + 3] = bf16r(m3);
      }
    }
    __syncthreads();

    {  // Gershgorin (4 threads/row) -> Chebyshev-1 init params
      const int row = tid & 63, part = tid >> 6;
      float s = 0.f;
      #pragma unroll
      for (int k = 0; k < 16; ++k) s += fabsf(Ms[row * 65 + part * 16 + k]);
      radp[part * 64 + row] = s;
    }
    __syncthreads();
    if (tid < 64) {
      const float diag = Ms[tid * 65 + tid];
      const float rad = radp[tid] + radp[64 + tid] + radp[128 + tid] +
                        radp[192 + tid] - fabsf(diag);
      float lo = diag - rad, hi = diag + rad;
      for (int off = 32; off; off >>= 1) {
        lo = fminf(lo, __shfl_down(lo, off));
        hi = fmaxf(hi, __shfl_down(hi, off));
      }
      if (tid == 0) {
        const float a = fmaxf(lo, lam);   // spectrum >= lam (StS is PSD)
        const float bb = hi;
        const float s = a + bb, d = bb - a;
        scal[0] = s;
        scal[1] = 8.f / (2.f * s * s - d * d);   // X0 = theta*(s*I - M)
      }
    }
    __syncthreads();
    const float s0 = scal[0], theta = scal[1];

    for (int e = tid; e < 4096; e += 256) {      // X0 only (Mb done in sum)
      const int i = e >> 6, j = e & 63;
      Xa[i * 72 + j] = bf16r(theta * (((i == j) ? s0 : 0.f) - Ms[i * 65 + j]));
    }
    __syncthreads();

    // NS iteration 1: Xc = 2*Xa - (Xa*M)*Xa
    {
      f32x4 t[2][2];
      ZERO_ACC2(t)
      mm64q(Xa, Mb, t, r, g, wr, wc);
      #pragma unroll
      for (int i = 0; i < 2; ++i)
        #pragma unroll
        for (int j = 0; j < 2; ++j)
          #pragma unroll
          for (int q = 0; q < 4; ++q) {
            const int row = wr * 32 + i * 16 + g * 4 + q;
            const int col = wc * 32 + j * 16 + r;
            Tb[row * 72 + col] = bf16r(t[i][j][q]);
          }
    }
    __syncthreads();
    {
      f32x4 t[2][2];
      ZERO_ACC2(t)
      mm64q(Tb, Xa, t, r, g, wr, wc);
      #pragma unroll
      for (int i = 0; i < 2; ++i)
        #pragma unroll
        for (int j = 0; j < 2; ++j)
          #pragma unroll
          for (int q = 0; q < 4; ++q) {
            const int row = wr * 32 + i * 16 + g * 4 + q;
            const int col = wc * 32 + j * 16 + r;
            const int idx = row * 72 + col;
            Xc[idx] = bf16r(2.f * b2f(Xa[idx]) - t[i][j][q]);
          }
    }
    __syncthreads();
    // NS iteration 2 with fused B: B = (rho-1)I - rho*lam*(2*Xc - (Xc*M)*Xc)
    {
      f32x4 t[2][2];
      ZERO_ACC2(t)
      mm64q(Xc, Mb, t, r, g, wr, wc);
      #pragma unroll
      for (int i = 0; i < 2; ++i)
        #pragma unroll
        for (int j = 0; j < 2; ++j)
          #pragma unroll
          for (int q = 0; q < 4; ++q) {
            const int row = wr * 32 + i * 16 + g * 4 + q;
            const int col = wc * 32 + j * 16 + r;
            Tb[row * 72 + col] = bf16r(t[i][j][q]);
          }
    }
    __syncthreads();
    {
      f32x4 t[2][2];
      ZERO_ACC2(t)
      mm64q(Tb, Xc, t, r, g, wr, wc);
      #pragma unroll
      for (int i = 0; i < 2; ++i)
        #pragma unroll
        for (int j = 0; j < 2; ++j)
          #pragma unroll
          for (int q = 0; q < 4; ++q) {
            const int row = wr * 32 + i * 16 + g * 4 + q;
            const int col = wc * 32 + j * 16 + r;
            const int idx = row * 72 + col;
            const float x2 = 2.f * b2f(Xc[idx]) - t[i][j][q];
            Xa[idx] = bf16r(((row == col) ? (rho - 1.f) : 0.f) - rho * lam * x2);
          }
    }
    __syncthreads();
    {  // G = B*B ; store bf16(-G/100)
      f32x4 t[2][2];
      ZERO_ACC2(t)
      mm64q(Xa, Xa, t, r, g, wr, wc);
      #pragma unroll
      for (int i = 0; i < 2; ++i)
        #pragma unroll
        for (int j = 0; j < 2; ++j)
          #pragma unroll
          for (int q = 0; q < 4; ++q) {
            const int row = wr * 32 + i * 16 + g * 4 + q;
            const int col = wc * 32 + j * 16 + r;
            Gneg[n * 4096 + row * 64 + col] =
                (unsigned short)bf16r(t[i][j][q] * (-0.01f));
          }
    }
    __syncthreads();
    if (tid == 0) st_flag(&sflag[n], MAGIC);
    return;
  }

  // ======================= query dist + softmax + loss ======================
  const int img = (b - 30) * 4 + wave;
  const bool ok = img < NQ;
  const float sc = scale[0];                    // pre-poll loads (read-only)
  const int lab = ok ? label[img] : 0;
  f32x4 acc[4][4];
  ZERO_ACC4(acc)
  if (ok)                                       // overlaps the solve
    gram_accum(feat + (size_t)(NSUP + img) * IMG_STRIDE, acc, r, g);

  if (tid < 5) spin_rlx(&sflag[tid]);
  __syncthreads();
  __builtin_amdgcn_fence(__ATOMIC_ACQUIRE, "agent");   // one inv per wave

  // stage G (bf16) into LDS, row stride 80 shorts: the 4 g-rows of a dot read
  // land on banks {0-7},{8-15},{16-23},{24-31} — conflict-free.
  unsigned short* Gs = (unsigned short*)smem;   // 5*64*80 shorts = 51200 B
  for (int e = tid; e < 5120; e += 256) {
    const int e4 = e * 4;
    const int nn = e4 >> 12, rem = e4 & 4095, row = rem >> 6, col = rem & 63;
    *(short4v*)&Gs[nn * 5120 + row * 80 + col] = *(const short4v*)&Gneg[e4];
  }
  __syncthreads();

  float myloss = 0.f;
  float nl[5] = {0.f, 0.f, 0.f, 0.f, 0.f};
  if (ok) {
    #pragma unroll
    for (int R = 0; R < 4; ++R)
      #pragma unroll
      for (int C = 0; C < 4; ++C)
        #pragma unroll
        for (int q = 0; q < 4; ++q) {
          const int row = R * 16 + g * 4 + q, col = C * 16 + r;
          const float cv = acc[R][C][q] * (1.f / 64.f);
          const int idx = row * 80 + col;
          #pragma unroll
          for (int nn = 0; nn < 5; ++nn)
            nl[nn] += b2f((short)Gs[nn * 5120 + idx]) * cv;
        }
    #pragma unroll
    for (int nn = 0; nn < 5; ++nn)
      for (int off = 32; off; off >>= 1) nl[nn] += __shfl_down(nl[nn], off);

    if (lane == 0) {
      float mx = nl[0];
      #pragma unroll
      for (int nn = 1; nn < 5; ++nn) mx = fmaxf(mx, nl[nn]);
      float ex[5], se = 0.f;
      #pragma unroll
      for (int nn = 0; nn < 5; ++nn) { ex[nn] = expf(nl[nn] - mx); se += ex[nn]; }
      const float inv = 1.f / se;
      #pragma unroll
      for (int nn = 0; nn < 5; ++nn) out[img * 5 + nn] = ex[nn] * inv;

      float mx2 = nl[0] * sc;
      #pragma unroll
      for (int nn = 1; nn < 5; ++nn) mx2 = fmaxf(mx2, nl[nn] * sc);
      float se2 = 0.f;
      #pragma unroll
      for (int nn = 0; nn < 5; ++nn) se2 += expf(nl[nn] * sc - mx2);
      myloss = mx2 + logf(se2) - nl[lab] * sc;   // -log p[label]
    }
  }

  float* wl = (float*)(smem + 51200);
  if (lane == 0) wl[wave] = ok ? myloss : 0.f;
  __syncthreads();
  if (tid == 0) {
    blockloss[b - 30] = wl[0] + wl[1] + wl[2] + wl[3];
    st_flag(&lflag[b - 30], MAGIC);
  }

  if (b == 30 && wave == 0) {                   // final loss gather, block 30
    for (int i = lane; i < 113; i += 64) spin_rlx(&lflag[i]);
    __builtin_amdgcn_fence(__ATOMIC_ACQUIRE, "agent");
    float s = 0.f;
    for (int i = lane; i < 113; i += 64) s += blockloss[i];
    for (int off = 32; off; off >>= 1) s += __shfl_down(s, off);
    if (lane == 0) out[2250] = s / 450.f;
  }
}

extern "C" void kernel_launch(void* const* d_in, const int* in_sizes, int n_in,
                              void* d_out, int out_size, void* d_ws, size_t ws_size,
                              hipStream_t stream) {
  const float* feat  = (const float*)d_in[0];
  const int*   label = (const int*)d_in[1];
  const float* scale = (const float*)d_in[2];
  const float* rvec  = (const float*)d_in[3];
  float* out = (float*)d_out;

  char* ws = (char*)d_ws;
  float*          partial   = (float*)ws;                  //      0 .. 491520
  unsigned short* Gneg      = (unsigned short*)(ws + 491520);   // 40960 B
  float*          blockloss = (float*)(ws + 532480);       //   452 B
  unsigned*       flags     = (unsigned*)(ws + 532992);
  unsigned* gflag = flags;         // 30
  unsigned* sflag = flags + 32;    // 5
  unsigned* lflag = flags + 64;    // 113

  k_fused<<<dim3(143), dim3(256), 0, stream>>>(feat, label, scale, rvec, out,
                                               partial, Gneg, blockloss,
                                               gflag, sflag, lflag);
}